// Round 5
// baseline (165.859 us; speedup 1.0000x reference)
//
#include <hip/hip_runtime.h>

// Problem constants
#define B_DIM   4096
#define C_DIM   128
#define TOPK    8
#define K_INST  16
#define P_IDS   256          // B/K_INST
#define N_DIM   32768        // B*TOPK
#define INV_TEMP 20.0f       // 1/0.05
#define EPS 1e-6f

typedef unsigned short u16;
typedef __attribute__((ext_vector_type(8))) short bf16x8;
typedef __attribute__((ext_vector_type(4))) float f32x4;

struct alignas(8) U16x4 { u16 x, y, z, w; };

__device__ __forceinline__ u16 f2bf(float x) {
    union { float f; unsigned u; } v; v.f = x;
    unsigned r = v.u + 0x7fffu + ((v.u >> 16) & 1u);   // RTN-even
    return (u16)(r >> 16);
}

// DPP 16-lane-row reductions on the VALU pipe (no LDS traffic).
// ctrl MUST be a template param: __builtin_amdgcn_update_dpp requires an
// integer-constant-expression (R4: const-int param failed front-end check).
// After shr 1,2,4,8 lane 15 of each 16-lane row holds the full row reduction.
template <int CTRL>
__device__ __forceinline__ float dpp_shr_max(float x) {
    int s = __builtin_amdgcn_update_dpp(__float_as_int(x), __float_as_int(x),
                                        CTRL, 0xf, 0xf, false);
    return fmaxf(x, __int_as_float(s));
}
template <int CTRL>
__device__ __forceinline__ float dpp_shr_min(float x) {
    int s = __builtin_amdgcn_update_dpp(__float_as_int(x), __float_as_int(x),
                                        CTRL, 0xf, 0xf, false);
    return fminf(x, __int_as_float(s));
}

// ---------------- kernel 1: fp32 -> bf16 convert ----------------
#define NA4 131072           // 4096*128/4
#define NTOT4 1179648        // (4096*128 + 32768*128)/4
__global__ __launch_bounds__(256) void convert_bf16(const float4* __restrict__ fa,
                                                    const float4* __restrict__ fs,
                                                    u16* __restrict__ outA,
                                                    u16* __restrict__ outS) {
    int i = blockIdx.x * 256 + threadIdx.x;
    float4 v;
    u16* dst;
    if (i < NA4) { v = fa[i]; dst = outA + (size_t)i * 4; }
    else         { int j = i - NA4; v = fs[j]; dst = outS + (size_t)j * 4; }
    U16x4 o = { f2bf(v.x), f2bf(v.y), f2bf(v.z), f2bf(v.w) };
    *(U16x4*)dst = o;
}

// ---------------- kernel 2: register-only sim + per-block max/min ----------------
// grid (256 p, 8 rtg), block = 256 (4 waves as 2x2 over a 128x128 tile).
// NO LDS, NO barriers: B fragments persist in registers across 4 row-tile
// iterations; A fragments stream from global (L1/L2-hot: consecutive blocks
// share rtg). Epilogue: ni-fold + DPP row reduction, per-wn partials to global.
// pmax layout [2][4096][256] (row-major rows x p) so phase2 reads coalesce.
__global__ __launch_bounds__(256, 2) void phase1(const u16* __restrict__ A,    // [4096][128] bf16
                                                 const u16* __restrict__ Bm,   // [32768][128] bf16
                                                 float* __restrict__ pmax,     // [2][4096][256]
                                                 float* __restrict__ pmin)     // [2][4096]
{
    const int tid  = threadIdx.x;
    const int lane = tid & 63;
    const int wave = tid >> 6;
    const int wm   = wave >> 1;      // row half (0/1)
    const int wn   = wave & 1;       // col half (0/1)
    const int p    = blockIdx.x;     // identity col-block 0..255
    const int rtg  = blockIdx.y;     // row-tile group 0..7 (4 tiles each)
    const int col0 = p * 128;

    const int r = lane & 15;         // m/n index within 16
    const int g = lane >> 4;         // k-chunk index (k = kk*32 + g*8 + j)

    // ---- B fragments: loaded ONCE, persistent across all 4 iterations ----
    bf16x8 b[4][4];                  // [ni][kk], 64 VGPRs
    {
        const u16* brow = Bm + (size_t)(col0 + wn * 64 + r) * C_DIM + g * 8;
#pragma unroll
        for (int ni = 0; ni < 4; ++ni)
#pragma unroll
            for (int kk = 0; kk < 4; ++kk)
                b[ni][kk] = *(const bf16x8*)(brow + (size_t)ni * 16 * C_DIM + kk * 32);
    }

    const bool diag_blk = ((p >> 5) == rtg);
    const int  itd      = (p >> 3) & 3;       // which iter holds the diagonal
    const int  dloc     = p & 7;              // 16-row group within that tile

#pragma unroll 1                              // keep ONE iter's a+acc live (VGPR cap)
    for (int it = 0; it < 4; ++it) {
        const int rt   = rtg * 4 + it;
        const int row0 = rt * 128;

        // ---- A fragments for this row tile ----
        bf16x8 a[4][4];              // [mi][kk], 64 VGPRs
        {
            const u16* arow = A + (size_t)(row0 + wm * 64 + r) * C_DIM + g * 8;
#pragma unroll
            for (int mi = 0; mi < 4; ++mi)
#pragma unroll
                for (int kk = 0; kk < 4; ++kk)
                    a[mi][kk] = *(const bf16x8*)(arow + (size_t)mi * 16 * C_DIM + kk * 32);
        }

        // ---- 64 MFMAs ----
        f32x4 acc[4][4] = {};        // [mi][ni], 64 VGPRs
#pragma unroll
        for (int kk = 0; kk < 4; ++kk)
#pragma unroll
            for (int mi = 0; mi < 4; ++mi)
#pragma unroll
                for (int ni = 0; ni < 4; ++ni)
                    acc[mi][ni] = __builtin_amdgcn_mfma_f32_16x16x32_bf16(a[mi][kk], b[ni][kk], acc[mi][ni], 0, 0, 0);

        // ---- epilogue: per-row max over this wave's 64 cols ----
        // C/D: col = wn*64 + ni*16 + r, row = wm*64 + mi*16 + g*4 + rr
        float pm[4][4];
#pragma unroll
        for (int mi = 0; mi < 4; ++mi)
#pragma unroll
            for (int rr = 0; rr < 4; ++rr) {
                float m = fmaxf(fmaxf(acc[mi][0][rr], acc[mi][1][rr]),
                                fmaxf(acc[mi][2][rr], acc[mi][3][rr]));
                pm[mi][rr] = m;
            }
        // DPP reduce over r (16-lane rows); lane 15 of each row holds the max.
#pragma unroll
        for (int mi = 0; mi < 4; ++mi)
#pragma unroll
            for (int rr = 0; rr < 4; ++rr) {
                float m = pm[mi][rr];
                m = dpp_shr_max<0x111>(m);
                m = dpp_shr_max<0x112>(m);
                m = dpp_shr_max<0x114>(m);
                m = dpp_shr_max<0x118>(m);
                pm[mi][rr] = m;
            }
        if ((lane & 15) == 15) {
#pragma unroll
            for (int mi = 0; mi < 4; ++mi)
#pragma unroll
                for (int rr = 0; rr < 4; ++rr) {
                    const int row = row0 + wm * 64 + mi * 16 + g * 4 + rr;
                    pmax[((size_t)wn * B_DIM + row) * P_IDS + p] = pm[mi][rr];
                }
        }

        // ---- diagonal min (only the wave-pair owning the anchor rows) ----
        // mi must be a COMPILE-TIME index into acc (R1 lesson: dynamic index
        // demotes accumulators to scratch -> 4 GB spill).
        if (diag_blk && it == itd && wm == (dloc >> 2)) {
            const int misel = dloc & 3;
            float nm[4];
#pragma unroll
            for (int mi = 0; mi < 4; ++mi) {
                if (mi == misel) {
#pragma unroll
                    for (int rr = 0; rr < 4; ++rr)
                        nm[rr] = fminf(fminf(acc[mi][0][rr], acc[mi][1][rr]),
                                       fminf(acc[mi][2][rr], acc[mi][3][rr]));
                }
            }
#pragma unroll
            for (int rr = 0; rr < 4; ++rr) {
                float m = nm[rr];
                m = dpp_shr_min<0x111>(m);
                m = dpp_shr_min<0x112>(m);
                m = dpp_shr_min<0x114>(m);
                m = dpp_shr_min<0x118>(m);
                nm[rr] = m;
            }
            if ((lane & 15) == 15) {
#pragma unroll
                for (int rr = 0; rr < 4; ++rr)
                    pmin[(size_t)wn * B_DIM + p * 16 + g * 4 + rr] = nm[rr];
            }
        }
    }
}

// ---------------- kernel 3: per-row loss + mean ----------------
// grid 256 blocks x 256 threads; wave handles 4 rows, coalesced [row][p] reads.
__global__ __launch_bounds__(256) void phase2(const float* __restrict__ pmax,  // [2][4096][256]
                                              const float* __restrict__ pmin,  // [2][4096]
                                              const int* __restrict__ labels,
                                              float* __restrict__ out) {
    const int tid  = threadIdx.x;
    const int lane = tid & 63;
    const int w    = tid >> 6;
    const int base = blockIdx.x * 16 + w * 4;
    float lsum = 0.f;
#pragma unroll
    for (int q = 0; q < 4; ++q) {
        const int bb = base + q;
        const int pid = labels[bb];
        const float* r0 = pmax + (size_t)bb * P_IDS;
        const float* r1 = pmax + ((size_t)B_DIM + bb) * P_IDS;
        float s = 0.f;
#pragma unroll
        for (int j = 0; j < 4; ++j) {
            const int pp = j * 64 + lane;
            const float v = fmaxf(r0[pp], r1[pp]);
            s += (pp == pid) ? 0.f : __expf(v * INV_TEMP);
        }
#pragma unroll
        for (int off = 1; off < 64; off <<= 1)
            s += __shfl_xor(s, off, 64);
        if (lane == 0) {
            const float mn  = fminf(pmin[bb], pmin[B_DIM + bb]);
            const float pos = __expf(mn * INV_TEMP);
            lsum += -__logf(pos / (pos + s + EPS) + EPS);
        }
    }
    __shared__ float pb[4];
    if (lane == 0) pb[w] = lsum;
    __syncthreads();
    if (tid == 0)
        atomicAdd(out, (pb[0] + pb[1] + pb[2] + pb[3]) * (1.0f / (float)B_DIM));
}

extern "C" void kernel_launch(void* const* d_in, const int* in_sizes, int n_in,
                              void* d_out, int out_size, void* d_ws, size_t ws_size,
                              hipStream_t stream) {
    const float* feats   = (const float*)d_in[0];   // [4096,128]
    const float* feats_s = (const float*)d_in[1];   // [4096,8,128]
    const int*   labels  = (const int*)d_in[2];     // [4096]
    float* out = (float*)d_out;

    // workspace: bf16 A (1 MB) | bf16 S (8 MB) | pmax (8 MB) | pmin (32 KB)
    u16* wsA = (u16*)d_ws;
    u16* wsS = wsA + (size_t)B_DIM * C_DIM;
    float* pmax = (float*)((char*)d_ws + (9u << 20));
    float* pmin = pmax + (size_t)2 * B_DIM * P_IDS;

    hipMemsetAsync(d_out, 0, sizeof(float), stream);
    convert_bf16<<<NTOT4 / 256, 256, 0, stream>>>((const float4*)feats, (const float4*)feats_s, wsA, wsS);
    dim3 g1(P_IDS, 8);
    phase1<<<g1, 256, 0, stream>>>(wsA, wsS, pmax, pmin);
    phase2<<<P_IDS, 256, 0, stream>>>(pmax, pmin, labels, out);
}

// Round 6
// 159.548 us; speedup vs baseline: 1.0396x; 1.0396x over previous
//
#include <hip/hip_runtime.h>

// Problem constants
#define B_DIM   4096
#define C_DIM   128
#define TOPK    8
#define K_INST  16
#define P_IDS   256          // B/K_INST
#define N_DIM   32768        // B*TOPK
#define INV_TEMP 20.0f       // 1/0.05
#define EPS 1e-6f

typedef unsigned short u16;
typedef __attribute__((ext_vector_type(8))) short bf16x8;
typedef __attribute__((ext_vector_type(4))) float f32x4;

struct alignas(8) U16x4 { u16 x, y, z, w; };

__device__ __forceinline__ u16 f2bf(float x) {
    union { float f; unsigned u; } v; v.f = x;
    unsigned r = v.u + 0x7fffu + ((v.u >> 16) & 1u);   // RTN-even
    return (u16)(r >> 16);
}

// DPP 16-lane-row reductions on the VALU pipe (no LDS traffic).
// ctrl MUST be a template param (integer-constant-expression required).
// After shr 1,2,4,8 lane 15 of each 16-lane row holds the full row reduction.
template <int CTRL>
__device__ __forceinline__ float dpp_shr_max(float x) {
    int s = __builtin_amdgcn_update_dpp(__float_as_int(x), __float_as_int(x),
                                        CTRL, 0xf, 0xf, false);
    return fmaxf(x, __int_as_float(s));
}
template <int CTRL>
__device__ __forceinline__ float dpp_shr_min(float x) {
    int s = __builtin_amdgcn_update_dpp(__float_as_int(x), __float_as_int(x),
                                        CTRL, 0xf, 0xf, false);
    return fminf(x, __int_as_float(s));
}

// ---------------- kernel 1: fp32 -> bf16 convert ----------------
#define NA4 131072           // 4096*128/4
#define NTOT4 1179648        // (4096*128 + 32768*128)/4
__global__ __launch_bounds__(256) void convert_bf16(const float4* __restrict__ fa,
                                                    const float4* __restrict__ fs,
                                                    u16* __restrict__ outA,
                                                    u16* __restrict__ outS) {
    int i = blockIdx.x * 256 + threadIdx.x;
    float4 v;
    u16* dst;
    if (i < NA4) { v = fa[i]; dst = outA + (size_t)i * 4; }
    else         { int j = i - NA4; v = fs[j]; dst = outS + (size_t)j * 4; }
    U16x4 o = { f2bf(v.x), f2bf(v.y), f2bf(v.z), f2bf(v.w) };
    *(U16x4*)dst = o;
}

// ---------------- kernel 2: register-only sim + per-block max/min ----------------
// grid (256 p, 8 rtg), block = 256 (4 waves as 2x2 over a 128x128 tile).
// NO LDS, NO barriers: B fragments persist in registers across 4 row-tile
// iterations; A fragments stream from global (L2-hot: blocks sharing rtg reuse
// the same A tile). acc lives in AGPRs (unified file).
//
// Output layout pmax[wn][p][row] ([2][256][4096]): each store quad fills one
// 64B line of 16 consecutive rows owned EXCLUSIVELY by this block. R5's
// [wn][row][p] layout had 16 blocks (different XCDs) dirtying each line ->
// 65.6 MB of partial-line HBM write-backs (8x amplification) that throttled
// the whole kernel. Exclusive full lines -> 8 MB.
__global__ __launch_bounds__(256, 2) void phase1(const u16* __restrict__ A,    // [4096][128] bf16
                                                 const u16* __restrict__ Bm,   // [32768][128] bf16
                                                 float* __restrict__ pmax,     // [2][256][4096]
                                                 float* __restrict__ pmin)     // [2][4096]
{
    const int tid  = threadIdx.x;
    const int lane = tid & 63;
    const int wave = tid >> 6;
    const int wm   = wave >> 1;      // row half (0/1)
    const int wn   = wave & 1;       // col half (0/1)
    const int p    = blockIdx.x;     // identity col-block 0..255
    const int rtg  = blockIdx.y;     // row-tile group 0..7 (4 tiles each)
    const int col0 = p * 128;

    const int r = lane & 15;         // m/n index within 16
    const int g = lane >> 4;         // k-chunk index (k = kk*32 + g*8 + j)

    // ---- B fragments: loaded ONCE, persistent across all 4 iterations ----
    bf16x8 b[4][4];                  // [ni][kk], 64 VGPRs
    {
        const u16* brow = Bm + (size_t)(col0 + wn * 64 + r) * C_DIM + g * 8;
#pragma unroll
        for (int ni = 0; ni < 4; ++ni)
#pragma unroll
            for (int kk = 0; kk < 4; ++kk)
                b[ni][kk] = *(const bf16x8*)(brow + (size_t)ni * 16 * C_DIM + kk * 32);
    }

    const bool diag_blk = ((p >> 5) == rtg);
    const int  itd      = (p >> 3) & 3;       // which iter holds the diagonal
    const int  dloc     = p & 7;              // 16-row group within that tile

    float* const pmax_w = pmax + ((size_t)wn * P_IDS + p) * B_DIM;

#pragma unroll 1                              // keep ONE iter's a+acc live (VGPR cap)
    for (int it = 0; it < 4; ++it) {
        const int rt   = rtg * 4 + it;
        const int row0 = rt * 128;

        // ---- A fragments for this row tile ----
        bf16x8 a[4][4];              // [mi][kk], 64 VGPRs
        {
            const u16* arow = A + (size_t)(row0 + wm * 64 + r) * C_DIM + g * 8;
#pragma unroll
            for (int mi = 0; mi < 4; ++mi)
#pragma unroll
                for (int kk = 0; kk < 4; ++kk)
                    a[mi][kk] = *(const bf16x8*)(arow + (size_t)mi * 16 * C_DIM + kk * 32);
        }

        // ---- 64 MFMAs ----
        f32x4 acc[4][4] = {};        // [mi][ni], 64 AGPRs
#pragma unroll
        for (int kk = 0; kk < 4; ++kk)
#pragma unroll
            for (int mi = 0; mi < 4; ++mi)
#pragma unroll
                for (int ni = 0; ni < 4; ++ni)
                    acc[mi][ni] = __builtin_amdgcn_mfma_f32_16x16x32_bf16(a[mi][kk], b[ni][kk], acc[mi][ni], 0, 0, 0);

        // ---- epilogue: per-row max over this wave's 64 cols ----
        // C/D: col = wn*64 + ni*16 + r, row = wm*64 + mi*16 + g*4 + rr
        float pm[4][4];
#pragma unroll
        for (int mi = 0; mi < 4; ++mi)
#pragma unroll
            for (int rr = 0; rr < 4; ++rr) {
                float m = fmaxf(fmaxf(acc[mi][0][rr], acc[mi][1][rr]),
                                fmaxf(acc[mi][2][rr], acc[mi][3][rr]));
                pm[mi][rr] = m;
            }
        // DPP reduce over r (16-lane rows); lane 15 of each row holds the max.
#pragma unroll
        for (int mi = 0; mi < 4; ++mi)
#pragma unroll
            for (int rr = 0; rr < 4; ++rr) {
                float m = pm[mi][rr];
                m = dpp_shr_max<0x111>(m);
                m = dpp_shr_max<0x112>(m);
                m = dpp_shr_max<0x114>(m);
                m = dpp_shr_max<0x118>(m);
                pm[mi][rr] = m;
            }
        if ((lane & 15) == 15) {
            // Active lanes: g=0..3. For fixed (mi,rr) addresses are
            // row0+wm*64+mi*16+g*4+rr -> 4B stores 16B apart; the 4 rr-unrolled
            // stores fill the full 64B line rows [mi*16, mi*16+16) exclusively.
#pragma unroll
            for (int mi = 0; mi < 4; ++mi)
#pragma unroll
                for (int rr = 0; rr < 4; ++rr) {
                    const int row = row0 + wm * 64 + mi * 16 + g * 4 + rr;
                    pmax_w[row] = pm[mi][rr];
                }
        }

        // ---- diagonal min (only the wave-pair owning the anchor rows) ----
        // mi must be a COMPILE-TIME index into acc (R1 lesson: dynamic index
        // demotes accumulators to scratch -> 4 GB spill).
        if (diag_blk && it == itd && wm == (dloc >> 2)) {
            const int misel = dloc & 3;
            float nm[4];
#pragma unroll
            for (int mi = 0; mi < 4; ++mi) {
                if (mi == misel) {
#pragma unroll
                    for (int rr = 0; rr < 4; ++rr)
                        nm[rr] = fminf(fminf(acc[mi][0][rr], acc[mi][1][rr]),
                                       fminf(acc[mi][2][rr], acc[mi][3][rr]));
                }
            }
#pragma unroll
            for (int rr = 0; rr < 4; ++rr) {
                float m = nm[rr];
                m = dpp_shr_min<0x111>(m);
                m = dpp_shr_min<0x112>(m);
                m = dpp_shr_min<0x114>(m);
                m = dpp_shr_min<0x118>(m);
                nm[rr] = m;
            }
            if ((lane & 15) == 15) {
                // 16 contiguous floats per (wn,p): exactly one exclusive 64B line.
#pragma unroll
                for (int rr = 0; rr < 4; ++rr)
                    pmin[(size_t)wn * B_DIM + p * 16 + g * 4 + rr] = nm[rr];
            }
        }
    }
}

// ---------------- kernel 3: per-row loss + mean ----------------
// grid 64 blocks x 256 threads. lane = row (coalesced 256B reads in the
// [wn][p][row] layout), wave = 64-wide p-slice. No per-p shuffles.
__global__ __launch_bounds__(256) void phase2(const float* __restrict__ pmax,  // [2][256][4096]
                                              const float* __restrict__ pmin,  // [2][4096]
                                              const int* __restrict__ labels,
                                              float* __restrict__ out) {
    const int tid  = threadIdx.x;
    const int lane = tid & 63;
    const int w    = tid >> 6;
    const int row  = blockIdx.x * 64 + lane;
    const int pid  = labels[row];
    const float* b0 = pmax + row;                          // + p*B_DIM
    const float* b1 = pmax + (size_t)P_IDS * B_DIM + row;
    float s = 0.f;
#pragma unroll 8
    for (int j = 0; j < 64; ++j) {
        const int p = w * 64 + j;
        const float v = fmaxf(b0[(size_t)p * B_DIM], b1[(size_t)p * B_DIM]);
        s += (p == pid) ? 0.f : __expf(v * INV_TEMP);
    }
    __shared__ float part[4][64];
    part[w][lane] = s;
    __syncthreads();
    if (tid < 64) {
        const int rr = blockIdx.x * 64 + tid;
        const float neg = part[0][tid] + part[1][tid] + part[2][tid] + part[3][tid];
        const float mn  = fminf(pmin[rr], pmin[B_DIM + rr]);
        const float pos = __expf(mn * INV_TEMP);
        float loss = -__logf(pos / (pos + neg + EPS) + EPS);
#pragma unroll
        for (int off = 32; off > 0; off >>= 1)
            loss += __shfl_down(loss, off, 64);
        if (tid == 0) atomicAdd(out, loss * (1.0f / (float)B_DIM));
    }
}

extern "C" void kernel_launch(void* const* d_in, const int* in_sizes, int n_in,
                              void* d_out, int out_size, void* d_ws, size_t ws_size,
                              hipStream_t stream) {
    const float* feats   = (const float*)d_in[0];   // [4096,128]
    const float* feats_s = (const float*)d_in[1];   // [4096,8,128]
    const int*   labels  = (const int*)d_in[2];     // [4096]
    float* out = (float*)d_out;

    // workspace: bf16 A (1 MB) | bf16 S (8 MB) | pmax (8 MB) | pmin (32 KB)
    u16* wsA = (u16*)d_ws;
    u16* wsS = wsA + (size_t)B_DIM * C_DIM;
    float* pmax = (float*)((char*)d_ws + (9u << 20));
    float* pmin = pmax + (size_t)2 * P_IDS * B_DIM;

    hipMemsetAsync(d_out, 0, sizeof(float), stream);
    convert_bf16<<<NTOT4 / 256, 256, 0, stream>>>((const float4*)feats, (const float4*)feats_s, wsA, wsS);
    dim3 g1(P_IDS, 8);
    phase1<<<g1, 256, 0, stream>>>(wsA, wsS, pmax, pmin);
    phase2<<<B_DIM / 64, 256, 0, stream>>>(pmax, pmin, labels, out);
}

// Round 7
// 121.248 us; speedup vs baseline: 1.3679x; 1.3159x over previous
//
#include <hip/hip_runtime.h>

// Problem constants
#define B_DIM   4096
#define C_DIM   128
#define TOPK    8
#define K_INST  16
#define P_IDS   256          // B/K_INST
#define N_DIM   32768        // B*TOPK
#define INV_TEMP 20.0f       // 1/0.05
#define EPS 1e-6f
#define TSZ 16384            // u16 elements per 32 KB A-tile LDS buffer

typedef unsigned short u16;
typedef __attribute__((ext_vector_type(8))) short bf16x8;
typedef __attribute__((ext_vector_type(4))) float f32x4;

struct alignas(8) U16x4 { u16 x, y, z, w; };

__device__ __forceinline__ u16 f2bf(float x) {
    union { float f; unsigned u; } v; v.f = x;
    unsigned r = v.u + 0x7fffu + ((v.u >> 16) & 1u);   // RTN-even
    return (u16)(r >> 16);
}

__device__ __forceinline__ void gload_lds16(const u16* g, u16* l) {
    __builtin_amdgcn_global_load_lds(
        (__attribute__((address_space(1))) void*)g,
        (__attribute__((address_space(3))) void*)l,
        16, 0, 0);
}

// DPP 16-lane-row reductions on the VALU pipe (ctrl must be template const).
template <int CTRL>
__device__ __forceinline__ float dpp_shr_max(float x) {
    int s = __builtin_amdgcn_update_dpp(__float_as_int(x), __float_as_int(x),
                                        CTRL, 0xf, 0xf, false);
    return fmaxf(x, __int_as_float(s));
}
template <int CTRL>
__device__ __forceinline__ float dpp_shr_min(float x) {
    int s = __builtin_amdgcn_update_dpp(__float_as_int(x), __float_as_int(x),
                                        CTRL, 0xf, 0xf, false);
    return fminf(x, __int_as_float(s));
}

// ---------------- kernel 1: fp32 -> bf16 convert (A only, 1 MB out) ----------------
#define NA4 131072           // 4096*128/4
__global__ __launch_bounds__(256) void convert_bf16(const float4* __restrict__ fa,
                                                    u16* __restrict__ outA) {
    int i = blockIdx.x * 256 + threadIdx.x;
    float4 v = fa[i];
    U16x4 o = { f2bf(v.x), f2bf(v.y), f2bf(v.z), f2bf(v.w) };
    *(U16x4*)(outA + (size_t)i * 4) = o;
}

// ---------------- kernel 2: pipelined sim + per-block max/min ----------------
// grid (256 p, 2 h), block = 256 (4 waves as 2x2 over a 128x128 tile), 16 iters.
// R2/R3/R6 all plateaued ~80 us: ~320 MB of L2 re-reads with NO load/compute
// overlap (per-iter vmcnt(0) drains, ~1.6 waves/SIMD). Fix = m97-style async
// pipeline: double-buffered global_load_lds staging of A (DMA for it+1 issued
// before compute of it; one barrier/iter), B in registers (converted from fp32
// in-kernel, killing the feats_s convert pass).
// A LDS layout XOR-swizzled VIA THE GLOBAL SOURCE ADDRESS (global_load_lds dst
// is wave-uniform base + lane*16 — m104): 16B chunk (row,kc) lives at slot
// row*16 + (kc ^ (row&7)) -> ds_read_b128 spreads all 32 banks (2-way = free).
__global__ __launch_bounds__(256, 2) void phase1(const u16*  __restrict__ A,    // bf16 [4096][128]
                                                 const float* __restrict__ Bm32, // fp32 [32768][128]
                                                 float* __restrict__ pmax,      // [2][256][4096]
                                                 float* __restrict__ pmin)      // [2][4096]
{
    __shared__ u16 Als[2 * TSZ];      // 64 KB double buffer

    const int tid  = threadIdx.x;
    const int lane = tid & 63;
    const int wave = tid >> 6;
    const int wm   = wave >> 1;       // row half (0/1)
    const int wn   = wave & 1;        // col half (0/1)
    const int p    = blockIdx.x;      // identity col-block 0..255
    const int h    = blockIdx.y;      // row half of B_DIM: rows h*2048..+2047
    const int r    = lane & 15;
    const int g    = lane >> 4;

    // ---- staging address precompute: thread stages slots s = j*256+tid ----
    // slot s holds global chunk (row=s>>4, kc=(s&15)^((s>>4)&7)); for
    // s=j*256+tid: row = j*16+(tid>>4), kc = (tid&15)^((tid>>4)&7) (const in j).
    const int skc = (tid & 15) ^ ((tid >> 4) & 7);
    const u16* sbase = A + ((size_t)h * 2048 + (tid >> 4)) * C_DIM + skc * 8;

    // ---- prologue: DMA tile 0 -> buf0 (async) ----
    {
        u16* dst = &Als[tid * 8];
#pragma unroll
        for (int j = 0; j < 8; ++j)
            gload_lds16(sbase + (size_t)j * 16 * C_DIM, dst + j * 2048);
    }

    // ---- B fragments: fp32 -> bf16 in-register (one-time, 64 VGPRs) ----
    bf16x8 b[4][4];                   // [ni][kk]
    {
        const float* brow = Bm32 + (size_t)(p * 128 + wn * 64 + r) * C_DIM + g * 8;
#pragma unroll
        for (int ni = 0; ni < 4; ++ni)
#pragma unroll
            for (int kk = 0; kk < 4; ++kk) {
                const float* s0 = brow + (size_t)ni * 16 * C_DIM + kk * 32;
                float4 u0 = *(const float4*)s0;
                float4 u1 = *(const float4*)(s0 + 4);
                bf16x8 f;
                f[0] = (short)f2bf(u0.x); f[1] = (short)f2bf(u0.y);
                f[2] = (short)f2bf(u0.z); f[3] = (short)f2bf(u0.w);
                f[4] = (short)f2bf(u1.x); f[5] = (short)f2bf(u1.y);
                f[6] = (short)f2bf(u1.z); f[7] = (short)f2bf(u1.w);
                b[ni][kk] = f;
            }
    }

    const bool diag_blk = (h == (p >> 7));
    const int  itd      = (p >> 3) & 15;      // iter holding the anchor rows
    const int  dloc     = p & 7;              // 16-row group within that tile
    float* const pmax_w = pmax + ((size_t)wn * P_IDS + p) * B_DIM;

    int lofs = 0;
#pragma unroll 1
    for (int it = 0; it < 16; ++it) {
        // my DMA chunks + B loads done; barrier makes everyone's DMA visible
        // and gates reuse of the other buffer (all waves past last iter's reads).
        __builtin_amdgcn_s_waitcnt(0);
        __syncthreads();

        // prefetch tile it+1 into the other buffer — overlaps this iter's compute
        if (it < 15) {
            u16* dst = &Als[(lofs ^ TSZ) + tid * 8];
            const u16* src = sbase + (size_t)(it + 1) * 128 * C_DIM;
#pragma unroll
            for (int j = 0; j < 8; ++j)
                gload_lds16(src + (size_t)j * 16 * C_DIM, dst + j * 2048);
        }

        const int row0 = h * 2048 + it * 128;

        // ---- A fragments from swizzled LDS ----
        bf16x8 a[4][4];               // [mi][kk]
#pragma unroll
        for (int mi = 0; mi < 4; ++mi)
#pragma unroll
            for (int kk = 0; kk < 4; ++kk) {
                const int row  = wm * 64 + mi * 16 + r;
                const int slot = row * 16 + ((kk * 4 + g) ^ (row & 7));
                a[mi][kk] = *(const bf16x8*)&Als[lofs + slot * 8];
            }

        // ---- 64 MFMAs ----
        f32x4 acc[4][4] = {};
#pragma unroll
        for (int kk = 0; kk < 4; ++kk)
#pragma unroll
            for (int mi = 0; mi < 4; ++mi)
#pragma unroll
                for (int ni = 0; ni < 4; ++ni)
                    acc[mi][ni] = __builtin_amdgcn_mfma_f32_16x16x32_bf16(a[mi][kk], b[ni][kk], acc[mi][ni], 0, 0, 0);

        // ---- epilogue: per-row max over this wave's 64 cols ----
        // C/D: col = wn*64 + ni*16 + r, row = wm*64 + mi*16 + g*4 + rr
        float pm[4][4];
#pragma unroll
        for (int mi = 0; mi < 4; ++mi)
#pragma unroll
            for (int rr = 0; rr < 4; ++rr)
                pm[mi][rr] = fmaxf(fmaxf(acc[mi][0][rr], acc[mi][1][rr]),
                                   fmaxf(acc[mi][2][rr], acc[mi][3][rr]));
#pragma unroll
        for (int mi = 0; mi < 4; ++mi)
#pragma unroll
            for (int rr = 0; rr < 4; ++rr) {
                float m = pm[mi][rr];
                m = dpp_shr_max<0x111>(m);
                m = dpp_shr_max<0x112>(m);
                m = dpp_shr_max<0x114>(m);
                m = dpp_shr_max<0x118>(m);
                pm[mi][rr] = m;
            }
        if ((lane & 15) == 15) {
            // lanes g=0..3; rr-unrolled stores fill exclusive full 64B lines
            // (R5 lesson: shared lines -> 8x HBM write amplification).
#pragma unroll
            for (int mi = 0; mi < 4; ++mi)
#pragma unroll
                for (int rr = 0; rr < 4; ++rr) {
                    const int row = row0 + wm * 64 + mi * 16 + g * 4 + rr;
                    pmax_w[row] = pm[mi][rr];
                }
        }

        // ---- diagonal min (anchor identity's own block) ----
        // mi must stay COMPILE-TIME into acc (R1: dynamic index -> scratch spill).
        if (diag_blk && it == itd && wm == (dloc >> 2)) {
            const int misel = dloc & 3;
            float nm[4];
#pragma unroll
            for (int mi = 0; mi < 4; ++mi) {
                if (mi == misel) {
#pragma unroll
                    for (int rr = 0; rr < 4; ++rr)
                        nm[rr] = fminf(fminf(acc[mi][0][rr], acc[mi][1][rr]),
                                       fminf(acc[mi][2][rr], acc[mi][3][rr]));
                }
            }
#pragma unroll
            for (int rr = 0; rr < 4; ++rr) {
                float m = nm[rr];
                m = dpp_shr_min<0x111>(m);
                m = dpp_shr_min<0x112>(m);
                m = dpp_shr_min<0x114>(m);
                m = dpp_shr_min<0x118>(m);
                nm[rr] = m;
            }
            if ((lane & 15) == 15) {
#pragma unroll
                for (int rr = 0; rr < 4; ++rr)
                    pmin[(size_t)wn * B_DIM + p * 16 + g * 4 + rr] = nm[rr];
            }
        }

        lofs ^= TSZ;
    }
}

// ---------------- kernel 3: per-row loss + mean ----------------
// grid 64 blocks x 256 threads. lane = row (coalesced in [wn][p][row] layout),
// wave = 64-wide p-slice.
__global__ __launch_bounds__(256) void phase2(const float* __restrict__ pmax,  // [2][256][4096]
                                              const float* __restrict__ pmin,  // [2][4096]
                                              const int* __restrict__ labels,
                                              float* __restrict__ out) {
    const int tid  = threadIdx.x;
    const int lane = tid & 63;
    const int w    = tid >> 6;
    const int row  = blockIdx.x * 64 + lane;
    const int pid  = labels[row];
    const float* b0 = pmax + row;                          // + p*B_DIM
    const float* b1 = pmax + (size_t)P_IDS * B_DIM + row;
    float s = 0.f;
#pragma unroll 8
    for (int j = 0; j < 64; ++j) {
        const int p = w * 64 + j;
        const float v = fmaxf(b0[(size_t)p * B_DIM], b1[(size_t)p * B_DIM]);
        s += (p == pid) ? 0.f : __expf(v * INV_TEMP);
    }
    __shared__ float part[4][64];
    part[w][lane] = s;
    __syncthreads();
    if (tid < 64) {
        const int rr = blockIdx.x * 64 + tid;
        const float neg = part[0][tid] + part[1][tid] + part[2][tid] + part[3][tid];
        const float mn  = fminf(pmin[rr], pmin[B_DIM + rr]);
        const float pos = __expf(mn * INV_TEMP);
        float loss = -__logf(pos / (pos + neg + EPS) + EPS);
#pragma unroll
        for (int off = 32; off > 0; off >>= 1)
            loss += __shfl_down(loss, off, 64);
        if (tid == 0) atomicAdd(out, loss * (1.0f / (float)B_DIM));
    }
}

extern "C" void kernel_launch(void* const* d_in, const int* in_sizes, int n_in,
                              void* d_out, int out_size, void* d_ws, size_t ws_size,
                              hipStream_t stream) {
    const float* feats   = (const float*)d_in[0];   // [4096,128]
    const float* feats_s = (const float*)d_in[1];   // [4096,8,128] fp32 (read directly)
    const int*   labels  = (const int*)d_in[2];     // [4096]
    float* out = (float*)d_out;

    // workspace: bf16 A (1 MB) | pmax (8 MB) | pmin (32 KB)
    u16* wsA = (u16*)d_ws;
    float* pmax = (float*)((char*)d_ws + (1u << 20));
    float* pmin = pmax + (size_t)2 * P_IDS * B_DIM;

    hipMemsetAsync(d_out, 0, sizeof(float), stream);
    convert_bf16<<<NA4 / 256, 256, 0, stream>>>((const float4*)feats, wsA);
    dim3 g1(P_IDS, 2);
    phase1<<<g1, 256, 0, stream>>>(wsA, feats_s, pmax, pmin);
    phase2<<<B_DIM / 64, 256, 0, stream>>>(pmax, pmin, labels, out);
}

// Round 8
// 113.863 us; speedup vs baseline: 1.4567x; 1.0649x over previous
//
#include <hip/hip_runtime.h>

// Problem constants
#define B_DIM   4096
#define C_DIM   128
#define TOPK    8
#define K_INST  16
#define P_IDS   256          // B/K_INST
#define N_DIM   32768        // B*TOPK
#define INV_TEMP 20.0f       // 1/0.05
#define EPS 1e-6f
#define TSZ 16384            // u16 elements per 32 KB A-tile LDS buffer

typedef unsigned short u16;
typedef __attribute__((ext_vector_type(8))) short bf16x8;
typedef __attribute__((ext_vector_type(4))) float f32x4;

struct alignas(8) U16x4 { u16 x, y, z, w; };

__device__ __forceinline__ u16 f2bf(float x) {
    union { float f; unsigned u; } v; v.f = x;
    unsigned r = v.u + 0x7fffu + ((v.u >> 16) & 1u);   // RTN-even
    return (u16)(r >> 16);
}

__device__ __forceinline__ void gload_lds16(const u16* g, u16* l) {
    __builtin_amdgcn_global_load_lds(
        (__attribute__((address_space(1))) void*)g,
        (__attribute__((address_space(3))) void*)l,
        16, 0, 0);
}

// ---------------- kernel 1: fp32 -> bf16 convert (A only, 1 MB out) ----------------
#define NA4 131072           // 4096*128/4
__global__ __launch_bounds__(256) void convert_bf16(const float4* __restrict__ fa,
                                                    u16* __restrict__ outA) {
    int i = blockIdx.x * 256 + threadIdx.x;
    float4 v = fa[i];
    U16x4 o = { f2bf(v.x), f2bf(v.y), f2bf(v.z), f2bf(v.w) };
    *(U16x4*)(outA + (size_t)i * 4) = o;
}

// ---------------- kernel 2: pipelined sim + per-block max/min ----------------
// grid (256 p, 2 h), block = 256 (4 waves as 2x2 over a 128x128 tile), 16 iters.
// Double-buffered global_load_lds staging of A; B in registers (fp32->bf16
// in-kernel). A LDS layout XOR-swizzled via the GLOBAL source address.
//
// R8 changes vs R7 (561 TF-effective, MfmaUtil 22, VALU 40):
//  * MFMA operands SWAPPED: mfma(b, a, acc) computes S^T, so D's col=lane&15
//    indexes the A-row. Per-A-row max = fold 16 regs + shfl_xor(16,32) —
//    replaces 48 fold + 128 DPP-chained instrs; stores become 4 coalesced
//    64B-line stores (lanes 0-15).
//  * Partial drain before barrier: s_waitcnt vmcnt(4) (0xF74) + raw s_barrier
//    waits only the 8 prefetch DMAs (oldest), NOT the epilogue stores.
__global__ __launch_bounds__(256, 2) void phase1(const u16*  __restrict__ A,    // bf16 [4096][128]
                                                 const float* __restrict__ Bm32, // fp32 [32768][128]
                                                 float* __restrict__ pmax,      // [2][256][4096]
                                                 float* __restrict__ pmin)      // [2][4096]
{
    __shared__ u16 Als[2 * TSZ];      // 64 KB double buffer

    const int tid  = threadIdx.x;
    const int lane = tid & 63;
    const int wave = tid >> 6;
    const int wm   = wave >> 1;       // row half (0/1)
    const int wn   = wave & 1;        // col half (0/1)
    const int p    = blockIdx.x;      // identity col-block 0..255
    const int h    = blockIdx.y;      // row half of B_DIM: rows h*2048..+2047
    const int r    = lane & 15;
    const int g    = lane >> 4;

    // staging: thread stages slots s = j*256+tid; slot s holds global chunk
    // (row = s>>4, kc = (s&15)^((s>>4)&7)); kc is j-invariant.
    const int skc = (tid & 15) ^ ((tid >> 4) & 7);
    const u16* sbase = A + ((size_t)h * 2048 + (tid >> 4)) * C_DIM + skc * 8;

    // ---- prologue: DMA tile 0 -> buf0 (async) ----
    {
        u16* dst = &Als[tid * 8];
#pragma unroll
        for (int j = 0; j < 8; ++j)
            gload_lds16(sbase + (size_t)j * 16 * C_DIM, dst + j * 2048);
    }

    // ---- B fragments: fp32 -> bf16 in-register (one-time, 64 VGPRs) ----
    bf16x8 b[4][4];                   // [ni][kk]
    {
        const float* brow = Bm32 + (size_t)(p * 128 + wn * 64 + r) * C_DIM + g * 8;
#pragma unroll
        for (int ni = 0; ni < 4; ++ni)
#pragma unroll
            for (int kk = 0; kk < 4; ++kk) {
                const float* s0 = brow + (size_t)ni * 16 * C_DIM + kk * 32;
                float4 u0 = *(const float4*)s0;
                float4 u1 = *(const float4*)(s0 + 4);
                bf16x8 f;
                f[0] = (short)f2bf(u0.x); f[1] = (short)f2bf(u0.y);
                f[2] = (short)f2bf(u0.z); f[3] = (short)f2bf(u0.w);
                f[4] = (short)f2bf(u1.x); f[5] = (short)f2bf(u1.y);
                f[6] = (short)f2bf(u1.z); f[7] = (short)f2bf(u1.w);
                b[ni][kk] = f;
            }
    }

    const bool diag_blk = (h == (p >> 7));
    const int  itd      = (p >> 3) & 15;      // iter holding the anchor rows
    const int  dloc     = p & 7;              // 16-row group within that tile
    const int  wmsel    = dloc >> 2;
    const int  misel    = dloc & 3;
    float* const pmax_w = pmax + ((size_t)wn * P_IDS + p) * B_DIM;

    __builtin_amdgcn_s_waitcnt(0);            // prologue DMA + B loads done
    __builtin_amdgcn_s_barrier();

    int lofs = 0;
#pragma unroll 1
    for (int it = 0; it < 16; ++it) {
        // prefetch tile it+1 into the other buffer (overlaps this iter's compute)
        if (it < 15) {
            u16* dst = &Als[(lofs ^ TSZ) + tid * 8];
            const u16* src = sbase + (size_t)(it + 1) * 128 * C_DIM;
#pragma unroll
            for (int j = 0; j < 8; ++j)
                gload_lds16(src + (size_t)j * 16 * C_DIM, dst + j * 2048);
        }

        const int row0 = h * 2048 + it * 128;

        // ---- A fragments from swizzled LDS ----
        bf16x8 a[4][4];               // [mi][kk]
#pragma unroll
        for (int mi = 0; mi < 4; ++mi)
#pragma unroll
            for (int kk = 0; kk < 4; ++kk) {
                const int row  = wm * 64 + mi * 16 + r;
                const int slot = row * 16 + ((kk * 4 + g) ^ (row & 7));
                a[mi][kk] = *(const bf16x8*)&Als[lofs + slot * 8];
            }

        // ---- 64 MFMAs, operands swapped: D[n][m] (S^T tile) ----
        // C/D: col(lane&15) = m-sub, row(g*4+rr) = n-sub
        f32x4 acc[4][4] = {};         // [ni][mi]
#pragma unroll
        for (int kk = 0; kk < 4; ++kk)
#pragma unroll
            for (int ni = 0; ni < 4; ++ni)
#pragma unroll
                for (int mi = 0; mi < 4; ++mi)
                    acc[ni][mi] = __builtin_amdgcn_mfma_f32_16x16x32_bf16(b[ni][kk], a[mi][kk], acc[ni][mi], 0, 0, 0);

        // ---- epilogue: per-A-row max over this wave's 64 cols ----
        // For column m = mi*16 + r: 16 in-register n-values (ni x rr) at each
        // of 4 quads -> fold 15 fmax + 2 shuffles. Lanes 0-15 store one full
        // exclusive 64B line per mi (R5 lesson).
#pragma unroll
        for (int mi = 0; mi < 4; ++mi) {
            float m = acc[0][mi][0];
#pragma unroll
            for (int ni = 0; ni < 4; ++ni)
#pragma unroll
                for (int rr = 0; rr < 4; ++rr)
                    if (ni || rr) m = fmaxf(m, acc[ni][mi][rr]);
            m = fmaxf(m, __shfl_xor(m, 16, 64));
            m = fmaxf(m, __shfl_xor(m, 32, 64));
            if (lane < 16)
                pmax_w[row0 + wm * 64 + mi * 16 + lane] = m;
        }

        // ---- diagonal min (anchor identity's own rows) ----
        // misel stays COMPILE-TIME into acc (R1: dynamic index -> scratch spill).
        if (diag_blk && it == itd && wm == wmsel) {
            float m = 3.4e38f;
#pragma unroll
            for (int mi = 0; mi < 4; ++mi) {
                if (mi == misel) {
#pragma unroll
                    for (int ni = 0; ni < 4; ++ni)
#pragma unroll
                        for (int rr = 0; rr < 4; ++rr)
                            m = fminf(m, acc[ni][mi][rr]);
                }
            }
            m = fminf(m, __shfl_xor(m, 16, 64));
            m = fminf(m, __shfl_xor(m, 32, 64));
            if (lane < 16)
                pmin[(size_t)wn * B_DIM + p * 16 + lane] = m;
        }

        if (it < 15) {
            // drain ONLY the 8 prefetch DMAs (oldest vmem); epilogue stores
            // (<=8, newer) stay in flight. vmcnt=4, expcnt=7, lgkmcnt=15.
            __builtin_amdgcn_s_waitcnt(0xF74);
            __builtin_amdgcn_s_barrier();
        }
        lofs ^= TSZ;
    }
}

// ---------------- kernel 3: per-row loss + mean ----------------
// grid 256 blocks x 256 threads; block = 16 rows. Lanes r=0..15 read 64B-line
// chunks of [p][row]; 16 p-groups partial-sum via LDS.
__global__ __launch_bounds__(256) void phase2(const float* __restrict__ pmax,  // [2][256][4096]
                                              const float* __restrict__ pmin,  // [2][4096]
                                              const int* __restrict__ labels,
                                              float* __restrict__ out) {
    const int tid = threadIdx.x;
    const int r   = tid & 15;
    const int pg  = tid >> 4;
    const int row = blockIdx.x * 16 + r;
    const int pid = labels[row];
    const float* q0 = pmax + row;                          // + p*B_DIM
    const float* q1 = q0 + (size_t)P_IDS * B_DIM;
    float s = 0.f;
#pragma unroll
    for (int j = 0; j < 16; ++j) {
        const int p = pg * 16 + j;
        const float v = fmaxf(q0[(size_t)p * B_DIM], q1[(size_t)p * B_DIM]);
        s += (p == pid) ? 0.f : __expf(v * INV_TEMP);
    }
    __shared__ float part[16][17];
    part[pg][r] = s;
    __syncthreads();
    if (tid < 16) {
        float neg = 0.f;
#pragma unroll
        for (int j = 0; j < 16; ++j) neg += part[j][tid];
        const int rw = blockIdx.x * 16 + tid;
        const float mn  = fminf(pmin[rw], pmin[B_DIM + rw]);
        const float pos = __expf(mn * INV_TEMP);
        float loss = -__logf(pos / (pos + neg + EPS) + EPS);
        loss += __shfl_xor(loss, 1, 64);
        loss += __shfl_xor(loss, 2, 64);
        loss += __shfl_xor(loss, 4, 64);
        loss += __shfl_xor(loss, 8, 64);
        if (tid == 0) atomicAdd(out, loss * (1.0f / (float)B_DIM));
    }
}

extern "C" void kernel_launch(void* const* d_in, const int* in_sizes, int n_in,
                              void* d_out, int out_size, void* d_ws, size_t ws_size,
                              hipStream_t stream) {
    const float* feats   = (const float*)d_in[0];   // [4096,128]
    const float* feats_s = (const float*)d_in[1];   // [4096,8,128] fp32 (read directly)
    const int*   labels  = (const int*)d_in[2];     // [4096]
    float* out = (float*)d_out;

    // workspace: bf16 A (1 MB) | pmax (8 MB) | pmin (32 KB)
    u16* wsA = (u16*)d_ws;
    float* pmax = (float*)((char*)d_ws + (1u << 20));
    float* pmin = pmax + (size_t)2 * P_IDS * B_DIM;

    hipMemsetAsync(d_out, 0, sizeof(float), stream);
    convert_bf16<<<NA4 / 256, 256, 0, stream>>>((const float4*)feats, wsA);
    dim3 g1(P_IDS, 2);
    phase1<<<g1, 256, 0, stream>>>(wsA, feats_s, pmax, pmin);
    phase2<<<B_DIM / 16, 256, 0, stream>>>(pmax, pmin, labels, out);
}